// Round 9
// baseline (749.925 us; speedup 1.0000x reference)
//
#include <hip/hip_runtime.h>
#include <stdint.h>

// RPN GT matcher — exact JAX-semantics reimplementation.
// RNG (verified R3): partitionable counter-mode, counter=(0, flat_idx),
// 32-bit draw = o0 ^ o1; split(key,n)[i] = both words of tf(key,(0,i)).
#define NANCH   262144      // anchors (== 2^18, required by key packing)
#define NB      4           // batch
#define NG      64          // gt boxes per image
#define TGT_FG  153         // int(0.3*512)
#define SB      512         // sample batch
#define IDXMASK 262143u     // 2^18-1, anchor-index field in sort keys
#define NSH     8           // shards per batch (atomic-contention spreading)
#define SHCAP   (NANCH/NSH) // 32768 = 128 blocks * 256 anchors (exact fit)

// ---- workspace layout (bytes); harness poisons ws with 0xAA each launch ----
#define WS_PCNT     0                         // 64 counters on own 64B lines
#define WS_KTH      4096                      // NB u64
#define WS_TBG      4160                      // NB i32
#define WS_DOSAMP   4224                      // NB i32
#define WS_SAMPKEY  8192                      // NB*SB u64 -> ends 24576
#define WS_ZERO_WORDS 6144                    // zero [0, 24576) as u32
#define WS_GMAXC    32768                     // NB*256*64 f32 = 256 KB
#define WS_A2G      294912                    // NB*NANCH u8
#define WS_NEG      (WS_A2G + NB*NANCH)       // NB*NANCH u32 (8 shards/batch)
#define WS_POS      (WS_NEG + NB*NANCH*4)     // NB*NANCH u64 (~13.3 MB total)

#define PCNT_AT(pcnt, b, sh, L) ((pcnt)[(((b) * NSH + (sh)) * 2 + (L)) * 16])

struct RngKeys { uint32_t kp[NB][2]; uint32_t kn[NB][2]; };

// ---------------- threefry2x32-20, exactly as jax/_src/prng.py -------------
#define TFR(r) { x0 += x1; x1 = (x1 << (r)) | (x1 >> (32 - (r))); x1 ^= x0; }
__host__ __device__ inline void tf2x32(uint32_t k0, uint32_t k1,
                                       uint32_t x0, uint32_t x1,
                                       uint32_t &o0, uint32_t &o1) {
  uint32_t k2 = k0 ^ k1 ^ 0x1BD11BDAu;
  x0 += k0; x1 += k1;
  TFR(13) TFR(15) TFR(26) TFR(6)   x0 += k1; x1 += k2 + 1u;
  TFR(17) TFR(29) TFR(16) TFR(24)  x0 += k2; x1 += k0 + 2u;
  TFR(13) TFR(15) TFR(26) TFR(6)   x0 += k0; x1 += k1 + 3u;
  TFR(17) TFR(29) TFR(16) TFR(24)  x0 += k1; x1 += k2 + 4u;
  TFR(13) TFR(15) TFR(26) TFR(6)   x0 += k2; x1 += k0 + 5u;
  o0 = x0; o1 = x1;
}

// hash with per-element counter i: counter pair (0, i)
__host__ __device__ inline void tf_ctr(uint32_t k0, uint32_t k1, uint32_t i,
                                       uint32_t &o0, uint32_t &o1) {
  tf2x32(k0, k1, 0u, i, o0, o1);
}

// 32-bit random draw for flat element index: o0 ^ o1 (verified R3)
__device__ __forceinline__ uint32_t draw_bits(uint32_t k0, uint32_t k1,
                                              uint32_t idx) {
  uint32_t o0, o1;
  tf_ctr(k0, k1, idx, o0, o1);
  return o0 ^ o1;
}

// ---- threefry core for the categorical hot loop (rotate = alignbit) -------
#define ROTL1(x, r) __builtin_amdgcn_alignbit((x), (x), 32 - (r))
#define TFQ(r) { x0 += x1; x1 = ROTL1(x1, r); x1 ^= x0; }
// caller pre-applies +k0 to x0 and +k1 to x1 (x0 ctr word is 0 -> x0 = k0)
__device__ __forceinline__ uint32_t tf_bits_fast(uint32_t k0, uint32_t k1,
                                                 uint32_t k2, uint32_t x0,
                                                 uint32_t x1) {
  TFQ(13) TFQ(15) TFQ(26) TFQ(6)   x0 += k1; x1 += k2 + 1u;
  TFQ(17) TFQ(29) TFQ(16) TFQ(24)  x0 += k2; x1 += k0 + 2u;
  TFQ(13) TFQ(15) TFQ(26) TFQ(6)   x0 += k0; x1 += k1 + 3u;
  TFQ(17) TFQ(29) TFQ(16) TFQ(24)  x0 += k1; x1 += k2 + 4u;
  TFQ(13) TFQ(15) TFQ(26) TFQ(6)   x0 += k2; x1 += k0 + 5u;
  return x0 ^ x1;
}

// ------------- IoU, bit-identical across passes (no FP contraction) --------
__device__ __forceinline__ float box_area(float x1, float y1, float x2, float y2) {
#pragma clang fp contract(off)
  return ((x2 - x1) + 1.0f) * ((y2 - y1) + 1.0f);
}

__device__ __forceinline__ float iou_pair(float ax1, float ay1, float ax2, float ay2,
                                          float areaA, float gx1, float gy1,
                                          float gx2, float gy2, float areaB) {
#pragma clang fp contract(off)
  float ltx = fmaxf(ax1, gx1), lty = fmaxf(ay1, gy1);
  float rbx = fminf(ax2, gx2), rby = fminf(ay2, gy2);
  float w = fmaxf((rbx - ltx) + 1.0f, 0.0f);
  float h = fmaxf((rby - lty) + 1.0f, 0.0f);
  float inter = w * h;
  return inter / ((areaA + areaB) - inter);
}

// ---------------------------------------------------------------------------
// Pass A: per-chunk column maxima (no atomics). Block 0 additionally zeroes
// the 24KB control region (counters + samp_key) — replaces the memset
// dispatch; visibility to k_label is guaranteed by the dispatch boundary.
__global__ __launch_bounds__(256) void k_g2amax(
    const float4* __restrict__ boxes, const float4* __restrict__ gtb,
    const int* __restrict__ gti, const float* __restrict__ iminfo,
    float* __restrict__ gmaxc, unsigned int* __restrict__ wszero) {
  int bx = blockIdx.x;
  int t = threadIdx.x;
  if (bx == 0) {
    #pragma unroll
    for (int i = t; i < WS_ZERO_WORDS; i += 256) wszero[i] = 0u;
  }
  int b = bx >> 8, chunk = bx & 255;          // NANCH/1024 = 256 chunks/batch
  int j = t & 63, sub = t >> 6;
  float4 g = gtb[b * NG + j];
  bool valid = (gti[b * NG + j] == 0);
  float areaB = box_area(g.x, g.y, g.z, g.w);
  float thrx = iminfo[b * 3 + 1] + 1.0f;      // im_w + STRADDLE + 1
  float thry = iminfo[b * 3 + 0] + 1.0f;      // im_h + STRADDLE + 1
  float m = 0.0f;
  int base = chunk * 1024 + sub * 256;
  #pragma unroll 2
  for (int i = 0; i < 256; ++i) {
    float4 bb = boxes[base + i];              // same addr across wave: broadcast
    bool inside = (bb.x >= -0.0f) && (bb.y >= -0.0f) && (bb.z < thrx) && (bb.w < thry);
    float areaA = box_area(bb.x, bb.y, bb.z, bb.w);
    float v = iou_pair(bb.x, bb.y, bb.z, bb.w, areaA, g.x, g.y, g.z, g.w, areaB);
    v = (inside && valid) ? v : 0.0f;
    m = fmaxf(m, v);
  }
  __shared__ float red[4][64];
  red[sub][j] = m;
  __syncthreads();
  if (t < 64) {
    float mm = fmaxf(fmaxf(red[0][t], red[1][t]), fmaxf(red[2][t], red[3][t]));
    gmaxc[((b << 8) + chunk) * 64 + t] = mm;
  }
}

// Pass B: folds gmaxc -> g2a in-block (L2-resident, replaces k_g2afin), then
// labels init, argmax gt, with_max, pos/neg compaction (sharded lists,
// block-aggregated atomics on padded counters).
__global__ __launch_bounds__(256) void k_label(
    const float4* __restrict__ boxes, const float4* __restrict__ gtb,
    const int* __restrict__ gti, const float* __restrict__ iminfo,
    const float* __restrict__ gmaxc, float* __restrict__ labels,
    unsigned char* __restrict__ a2g, unsigned long long* __restrict__ pos_keys,
    unsigned int* __restrict__ neg_list, int* __restrict__ pcnt, RngKeys rk) {
  int bx = blockIdx.x;
  int b = bx >> 10, blk = bx & 1023;          // NANCH/256 = 1024 blocks/batch
  int t = threadIdx.x;
  int sh = blk & (NSH - 1);                   // 128 blocks/shard * 256 = SHCAP
  __shared__ float4 sg[NG];
  __shared__ float sab[NG], sval[NG], sadj[NG];
  __shared__ float red2[4][64];
  {  // fold 256 chunk-maxima for this batch (coalesced 64-lane rows)
    int j = t & 63, part = t >> 6;
    float m = 0.0f;
    for (int c = part * 64; c < part * 64 + 64; ++c)
      m = fmaxf(m, gmaxc[((b << 8) + c) * 64 + j]);
    red2[part][j] = m;
  }
  if (t < NG) {
    float4 g = gtb[b * NG + t];
    sg[t] = g;
    sab[t] = box_area(g.x, g.y, g.z, g.w);
    sval[t] = (gti[b * NG + t] == 0) ? 1.0f : 0.0f;
  }
  __syncthreads();
  if (t < 64) {
    float gm = fmaxf(fmaxf(red2[0][t], red2[1][t]), fmaxf(red2[2][t], red2[3][t]));
    sadj[t] = (gm == 0.0f) ? 1.0f : gm;       // avoid matching all-zero cols
  }
  __syncthreads();
  int a = blk * 256 + t;
  float4 bb = boxes[a];
  float thrx = iminfo[b * 3 + 1] + 1.0f, thry = iminfo[b * 3 + 0] + 1.0f;
  bool inside = (bb.x >= -0.0f) && (bb.y >= -0.0f) && (bb.z < thrx) && (bb.w < thry);
  float areaA = box_area(bb.x, bb.y, bb.z, bb.w);
  float maxv = 0.0f; int amax = 0; bool wm = false;
  #pragma unroll 8
  for (int j = 0; j < NG; ++j) {
    float4 g = sg[j];
    float v = iou_pair(bb.x, bb.y, bb.z, bb.w, areaA, g.x, g.y, g.z, g.w, sab[j]);
    v = (inside && (sval[j] != 0.0f)) ? v : 0.0f;
    wm = wm || (v == sadj[j]);                 // ensure_closest_box
    if (v > maxv) { maxv = v; amax = j; }      // first-max (== jnp.argmax)
  }
  bool pos = inside && (wm || (maxv >= 0.5f));
  bool neg = inside && (maxv < 0.3f);
  labels[b * NANCH + a] = pos ? 1.0f : -1.0f;
  a2g[b * NANCH + a] = (unsigned char)amax;
  // block-aggregated two-list compaction
  unsigned long long mpos = __ballot(pos);
  unsigned long long mneg = __ballot(neg);
  int lane = t & 63, wid = t >> 6;
  __shared__ int wc[4][2];
  __shared__ int bbase[2];
  if (lane == 0) { wc[wid][0] = __popcll(mpos); wc[wid][1] = __popcll(mneg); }
  __syncthreads();
  if (t == 0) {
    bbase[0] = atomicAdd(&PCNT_AT(pcnt, b, sh, 0),
                         wc[0][0] + wc[1][0] + wc[2][0] + wc[3][0]);
    bbase[1] = atomicAdd(&PCNT_AT(pcnt, b, sh, 1),
                         wc[0][1] + wc[1][1] + wc[2][1] + wc[3][1]);
  }
  __syncthreads();
  unsigned long long lt = (1ull << lane) - 1ull;
  if (pos) {
    int off = bbase[0] + __popcll(mpos & lt);
    for (int w = 0; w < wid; ++w) off += wc[w][0];
    // prio = uniform(kp,(n,)) -> monotone in bits>>9; key: prio desc, idx asc
    uint32_t bits = draw_bits(rk.kp[b][0], rk.kp[b][1], (uint32_t)a);
    unsigned long long key =
        (((unsigned long long)(bits >> 9)) << 18) | (unsigned long long)(IDXMASK - (uint32_t)a);
    pos_keys[(size_t)b * NANCH + (size_t)sh * SHCAP + off] = key;
  }
  if (neg) {
    int off = bbase[1] + __popcll(mneg & lt);
    for (int w = 0; w < wid; ++w) off += wc[w][1];
    neg_list[(size_t)b * NANCH + (size_t)sh * SHCAP + off] = (unsigned int)a;
  }
}

// Fused dispatch: blocks 0..3 = select (kth/tbg/dosamp via 41-round radix,
// hidden under cat's ~590us); blocks 4.. = categorical draws. cat computes
// targ from pcnt directly (no dependency on the select blocks).
__global__ __launch_bounds__(256) void k_catsel(
    const unsigned int* __restrict__ neg_list,
    const unsigned long long* __restrict__ pos_keys,
    const int* __restrict__ pcnt, unsigned long long* __restrict__ samp_key,
    unsigned long long* __restrict__ kth, int* __restrict__ tbg,
    int* __restrict__ dosamp, RngKeys rk) {
  int bx = blockIdx.x;
  int t = threadIdx.x, lane = t & 63, wid = t >> 6;

  if (bx < NB) {                         // ---------------- select path
    int b = bx;
    __shared__ int cw[4];
    int scnt[NSH]; int np = 0, nnb = 0;
    #pragma unroll
    for (int sh = 0; sh < NSH; ++sh) {
      scnt[sh] = PCNT_AT(pcnt, b, sh, 0);
      np += scnt[sh];
      nnb += PCNT_AT(pcnt, b, sh, 1);
    }
    int nf = np < TGT_FG ? np : TGT_FG;
    int targ = SB - nf;
    if (t == 0) { tbg[b] = targ; dosamp[b] = (nnb > targ) ? 1 : 0; }
    if (np <= TGT_FG) { if (t == 0) kth[b] = 0ull; return; }
    unsigned long long pref = 0ull;
    int r = TGT_FG;
    for (int bit = 40; bit >= 0; --bit) {
      unsigned long long cand = pref | (1ull << bit);
      unsigned long long mask = ~((1ull << bit) - 1ull);
      int c = 0;
      for (int sh = 0; sh < NSH; ++sh) {
        const unsigned long long* keys =
            pos_keys + (size_t)b * NANCH + (size_t)sh * SHCAP;
        for (int i = t; i < scnt[sh]; i += 256)
          c += ((keys[i] & mask) == cand) ? 1 : 0;
      }
      #pragma unroll
      for (int off = 32; off; off >>= 1) c += __shfl_xor(c, off, 64);
      __syncthreads();
      if (lane == 0) cw[wid] = c;
      __syncthreads();
      int total = cw[0] + cw[1] + cw[2] + cw[3];
      if (total >= r) pref = cand; else r -= total;
    }
    if (t == 0) kth[b] = pref;
    return;
  }

  // ---------------- cat path: per-draw key-argmax over the negatives.
  // gumbel strictly monotone in bits>>9; exact-bit ties -> smallest flat index.
  int bx2 = bx - NB;
  int sh = bx2 & (NSH - 1);              // shard = chunk of the negative list
  int pr = (bx2 >> 3) & 255;             // draw pair (s0 = 2*pr)
  int b  = bx2 >> 11;                    // batch
  int np = 0;
  #pragma unroll
  for (int s = 0; s < NSH; ++s) np += PCNT_AT(pcnt, b, s, 0);
  int targ = SB - (np < TGT_FG ? np : TGT_FG);
  int s0 = pr * 2;
  if (s0 >= targ) return;                // dead draws: reference discards them
  int nn = PCNT_AT(pcnt, b, sh, 1);
  uint32_t k0 = rk.kn[b][0], k1 = rk.kn[b][1];
  uint32_t k2 = k0 ^ k1 ^ 0x1BD11BDAu;
  uint32_t xb0 = ((uint32_t)s0 << 18) + k1;
  uint32_t xb1 = ((uint32_t)(s0 + 1) << 18) + k1;
  unsigned long long b0 = 0ull, b1 = 0ull;
  const unsigned int* nl = neg_list + (size_t)b * NANCH + (size_t)sh * SHCAP;
#define PROC1(A) { uint32_t a_ = (A); \
    unsigned long long inv64 = (unsigned long long)(IDXMASK - a_); \
    { uint32_t bits = tf_bits_fast(k0, k1, k2, k0, xb0 + a_); \
      unsigned long long key = (((unsigned long long)(bits >> 9)) << 18) | inv64; \
      if (key > b0) b0 = key; } \
    { uint32_t bits = tf_bits_fast(k0, k1, k2, k0, xb1 + a_); \
      unsigned long long key = (((unsigned long long)(bits >> 9)) << 18) | inv64; \
      if (key > b1) b1 = key; } }
  // uint4 main loop (4 elems, 8 hashes per iter), scalar tail
  int nv = nn >> 2;
  const uint4* nl4 = (const uint4*)nl;
  for (int iv = t; iv < nv; iv += 256) {
    uint4 q = nl4[iv];
    PROC1(q.x) PROC1(q.y) PROC1(q.z) PROC1(q.w)
  }
  for (int i = (nv << 2) + t; i < nn; i += 256) { PROC1(nl[i]) }
#undef PROC1
  // wave butterfly, then cross-wave merge
  #pragma unroll
  for (int off = 32; off; off >>= 1) {
    unsigned long long o0 = __shfl_xor(b0, off, 64); if (o0 > b0) b0 = o0;
    unsigned long long o1 = __shfl_xor(b1, off, 64); if (o1 > b1) b1 = o1;
  }
  __shared__ unsigned long long red[4][2];
  if (lane == 0) { red[wid][0] = b0; red[wid][1] = b1; }
  __syncthreads();
  if (t < 2) {
    int j = t;
    unsigned long long m = red[0][j];
    if (red[1][j] > m) m = red[1][j];
    if (red[2][j] > m) m = red[2][j];
    if (red[3][j] > m) m = red[3][j];
    if (s0 + j < targ) atomicMax(&samp_key[b * SB + s0 + j], m);
  }
}

// Set sampled negatives to 0 (runs BEFORE k_targets; with the fused disable
// in k_targets this reproduces the reference order disable-then-set(0),
// because the ==1 test there excludes anchors zeroed here).
__global__ __launch_bounds__(256) void k_scatter(
    const unsigned long long* __restrict__ samp_key, const int* __restrict__ tbg,
    const int* __restrict__ dosamp, float* __restrict__ labels) {
  int b = blockIdx.x >> 1;
  int s = ((blockIdx.x & 1) << 8) | threadIdx.x;
  if (!dosamp[b]) return;
  if (s < tbg[b]) {
    unsigned long long key = samp_key[b * SB + s];
    int a = (int)(IDXMASK - (uint32_t)(key & (unsigned long long)IDXMASK));
    labels[b * NANCH + a] = 0.0f;
  }
}

// Fused disable + bbox_transform_inv. For label==1 anchors, recompute the
// fg-priority key (1 threefry hash, bit-identical to k_label's) and compare
// with kth[b]: key < kth -> dropped positive -> label=-1, targets 0.
// kth==0 (np<=153) keeps all. Writes labels only when changed.
__global__ __launch_bounds__(256) void k_targets(
    const float4* __restrict__ boxes, const float4* __restrict__ gtb,
    const unsigned char* __restrict__ a2g, float* __restrict__ labels,
    const unsigned long long* __restrict__ kth, float4* __restrict__ tout,
    RngKeys rk) {
  int bx = blockIdx.x;
  int b = bx >> 10, blk = bx & 1023;
  int a = blk * 256 + threadIdx.x;
  float lab = labels[b * NANCH + a];
  float4 o = make_float4(0.f, 0.f, 0.f, 0.f);
  if (lab > 0.0f) {
    uint32_t bits = draw_bits(rk.kp[b][0], rk.kp[b][1], (uint32_t)a);
    unsigned long long key =
        (((unsigned long long)(bits >> 9)) << 18) | (unsigned long long)(IDXMASK - (uint32_t)a);
    if (key < kth[b]) {
      labels[b * NANCH + a] = -1.0f;           // disabled positive
    } else {
      float4 e = boxes[a];
      float4 g = gtb[b * NG + a2g[b * NANCH + a]];
      float ew = e.z - e.x + 1.0f, eh = e.w - e.y + 1.0f;
      float ecx = e.x + 0.5f * ew, ecy = e.y + 0.5f * eh;
      float gw = g.z - g.x + 1.0f, gh = g.w - g.y + 1.0f;
      float gcx = g.x + 0.5f * gw, gcy = g.y + 0.5f * gh;
      o.x = (gcx - ecx) / ew;
      o.y = (gcy - ecy) / eh;
      o.z = logf(gw / ew);
      o.w = logf(gh / eh);
    }
  }
  tout[(size_t)b * NANCH + a] = o;
}

// ---------------------------------------------------------------------------
extern "C" void kernel_launch(void* const* d_in, const int* in_sizes, int n_in,
                              void* d_out, int out_size, void* d_ws, size_t ws_size,
                              hipStream_t stream) {
  const float4* boxes  = (const float4*)d_in[0];
  const float4* gtb    = (const float4*)d_in[1];
  // d_in[2] = gt_labels: unused, exactly like the reference
  const int*    gti    = (const int*)d_in[3];
  const float*  iminfo = (const float*)d_in[4];
  float*  labels = (float*)d_out;                       // [B][N] as f32
  float4* tout   = (float4*)(labels + (size_t)NB * NANCH); // [B][N][4]

  char* wsb = (char*)d_ws;  // needs ~13.3 MB
  int*                pcnt     = (int*)(wsb + WS_PCNT);
  unsigned long long* kth      = (unsigned long long*)(wsb + WS_KTH);
  int*                tbg      = (int*)(wsb + WS_TBG);
  int*                dosamp   = (int*)(wsb + WS_DOSAMP);
  unsigned long long* samp_key = (unsigned long long*)(wsb + WS_SAMPKEY);
  float*              gmaxc    = (float*)(wsb + WS_GMAXC);
  unsigned char*      a2g      = (unsigned char*)(wsb + WS_A2G);
  unsigned int*       neg_list = (unsigned int*)(wsb + WS_NEG);
  unsigned long long* pos_keys = (unsigned long long*)(wsb + WS_POS);

  // Host-side key derivation: root=(0,42); split(root,4) -> per-image key;
  // split(key_b,2) -> (kp, kn). Split keys are the FULL 64-bit outputs.
  RngKeys rk;
  for (int b = 0; b < NB; ++b) {
    uint32_t a0, a1;
    tf_ctr(0u, 42u, (uint32_t)b, a0, a1);                // keys[b]
    tf_ctr(a0, a1, 0u, rk.kp[b][0], rk.kp[b][1]);        // subkey 0 = kp
    tf_ctr(a0, a1, 1u, rk.kn[b][0], rk.kn[b][1]);        // subkey 1 = kn
  }

  k_g2amax <<<NB * (NANCH / 1024), 256, 0, stream>>>(boxes, gtb, gti, iminfo,
                                                     gmaxc, (unsigned int*)wsb);
  k_label  <<<NB * (NANCH / 256), 256, 0, stream>>>(boxes, gtb, gti, iminfo, gmaxc,
                                                    labels, a2g, pos_keys, neg_list,
                                                    pcnt, rk);
  k_catsel <<<NB + NB * 256 * NSH, 256, 0, stream>>>(neg_list, pos_keys, pcnt,
                                                     samp_key, kth, tbg, dosamp, rk);
  k_scatter<<<NB * 2, 256, 0, stream>>>(samp_key, tbg, dosamp, labels);
  k_targets<<<NB * (NANCH / 256), 256, 0, stream>>>(boxes, gtb, a2g, labels,
                                                    kth, tout, rk);
}